// Round 5
// baseline (614.890 us; speedup 1.0000x reference)
//
#include <hip/hip_runtime.h>

#define T_DIM 2048
#define B_DIM 8192
#define GAMMA 0.99f
#define NCHUNK 256
#define CHUNK_L 8            // rows per chunk (NCHUNK*CHUNK_L == T_DIM)
#define NCG 8                // column groups
#define CG_COLS 1024         // columns per group (NCG*CG_COLS == B_DIM)

typedef float v4f __attribute__((ext_vector_type(4)));

__device__ __forceinline__ void nt_store4(float* p, float4 x) {
    __builtin_nontemporal_store(*(v4f*)&x, (v4f*)p);
}
__device__ __forceinline__ float4 f4_fma(float4 a, float4 b, float4 c) {
    return make_float4(fmaf(a.x, b.x, c.x), fmaf(a.y, b.y, c.y),
                       fmaf(a.z, b.z, c.z), fmaf(a.w, b.w, c.w));
}
__device__ __forceinline__ float4 f4_mul(float4 a, float4 b) {
    return make_float4(a.x * b.x, a.y * b.y, a.z * b.z, a.w * b.w);
}

// ---------------------------------------------------------------------------
// Single fused kernel: decoupled-lookback blocked scan (reverse over t).
// Block (g, by) handles chunk c = NCHUNK-1-by (so scan-predecessors = higher c
// = lower blockIdx = dispatched earlier; a block only ever waits on earlier
// blocks -> forward progress under in-order dispatch, rocPRIM-style).
// Phases: {read tlp,blp -> rho (NT store)} ; {read v,rew -> a,b} ;
// {publish agg, lookback for carry, sweep rows, NT-store vtrace, publish inc}.
// Outputs are NT stores: no L3 allocation -> inputs stay L3-resident.
// ---------------------------------------------------------------------------
__global__ __launch_bounds__(256) void vtrace_fused(
    const float* __restrict__ v, const float* __restrict__ rew,
    const float* __restrict__ tlp, const float* __restrict__ blp,
    float* __restrict__ out_v, float* __restrict__ out_rho,
    float* __restrict__ aggA, float* __restrict__ aggB,
    float* __restrict__ incl, int* flags)
{
    const int g    = blockIdx.x;
    const int c    = NCHUNK - 1 - blockIdx.y;
    const int col  = g * CG_COLS + threadIdx.x * 4;
    const int base = c * CHUNK_L * B_DIM + col;
    const bool last_chunk = (c == NCHUNK - 1);

    // ---- phase A: rho ----
    float4 t4[CHUNK_L], b4[CHUNK_L];
    #pragma unroll
    for (int r = 0; r < CHUNK_L; ++r) t4[r] = *(const float4*)(tlp + base + r * B_DIM);
    #pragma unroll
    for (int r = 0; r < CHUNK_L; ++r) b4[r] = *(const float4*)(blp + base + r * B_DIM);

    float4 rho[CHUNK_L];
    #pragma unroll
    for (int r = 0; r < CHUNK_L; ++r) {
        rho[r].x = fminf(1.f, __expf(t4[r].x - b4[r].x));
        rho[r].y = fminf(1.f, __expf(t4[r].y - b4[r].y));
        rho[r].z = fminf(1.f, __expf(t4[r].z - b4[r].z));
        rho[r].w = fminf(1.f, __expf(t4[r].w - b4[r].w));
        nt_store4(out_rho + base + r * B_DIM, rho[r]);
    }

    // ---- phase B: a = v + rho*(rew-v), b = gamma*rho (last row: a=v, b=0) ----
    float4 v4[CHUNK_L], r4[CHUNK_L];
    #pragma unroll
    for (int r = 0; r < CHUNK_L; ++r) v4[r] = *(const float4*)(v   + base + r * B_DIM);
    #pragma unroll
    for (int r = 0; r < CHUNK_L; ++r) r4[r] = *(const float4*)(rew + base + r * B_DIM);

    float4 a4[CHUNK_L], bv[CHUNK_L];
    #pragma unroll
    for (int r = 0; r < CHUNK_L; ++r) {
        if (last_chunk && r == CHUNK_L - 1) {        // global row T-1
            a4[r] = v4[r];
            bv[r] = make_float4(0.f, 0.f, 0.f, 0.f);
        } else {
            a4[r].x = fmaf(rho[r].x, r4[r].x - v4[r].x, v4[r].x);
            a4[r].y = fmaf(rho[r].y, r4[r].y - v4[r].y, v4[r].y);
            a4[r].z = fmaf(rho[r].z, r4[r].z - v4[r].z, v4[r].z);
            a4[r].w = fmaf(rho[r].w, r4[r].w - v4[r].w, v4[r].w);
            bv[r].x = GAMMA * rho[r].x;
            bv[r].y = GAMMA * rho[r].y;
            bv[r].z = GAMMA * rho[r].z;
            bv[r].w = GAMMA * rho[r].w;
        }
    }

    // ---- chunk composite: out[c*L] = A + B * out[(c+1)*L] ----
    float4 A  = make_float4(0.f, 0.f, 0.f, 0.f);
    float4 Bc = make_float4(1.f, 1.f, 1.f, 1.f);
    #pragma unroll
    for (int r = CHUNK_L - 1; r >= 0; --r) {
        A  = f4_fma(bv[r], A, a4[r]);
        Bc = f4_mul(Bc, bv[r]);
    }

    __shared__ int sh_f;
    float4 carry = make_float4(0.f, 0.f, 0.f, 0.f);

    if (!last_chunk) {
        // publish aggregate
        {
            const int e = c * B_DIM + col;
            *(float4*)(aggA + e) = A;
            *(float4*)(aggB + e) = Bc;
            __syncthreads();                 // drains each thread's stores (vmcnt 0)
            if (threadIdx.x == 0) {
                __threadfence();             // agent-scope writeback
                __hip_atomic_store(&flags[c * NCG + g], 1,
                                   __ATOMIC_RELEASE, __HIP_MEMORY_SCOPE_AGENT);
            }
        }
        // decoupled lookback: carry = out[(c+1)*L]
        float4 accA = make_float4(0.f, 0.f, 0.f, 0.f);
        float4 accB = make_float4(1.f, 1.f, 1.f, 1.f);
        int p = c + 1;
        for (;;) {
            if (threadIdx.x == 0) {
                int f;
                for (;;) {
                    f = __hip_atomic_load(&flags[p * NCG + g],
                                          __ATOMIC_ACQUIRE, __HIP_MEMORY_SCOPE_AGENT);
                    if (f) break;
                    __builtin_amdgcn_s_sleep(2);
                }
                sh_f = f;
            }
            __syncthreads();
            const int f = sh_f;
            const int e = p * B_DIM + col;
            if (f == 2) {
                const float4 inc4 = *(const float4*)(incl + e);
                carry = f4_fma(accB, inc4, accA);
                break;
            }
            const float4 pA = *(const float4*)(aggA + e);
            const float4 pB = *(const float4*)(aggB + e);
            accA = f4_fma(accB, pA, accA);
            accB = f4_mul(accB, pB);
            ++p;
            __syncthreads();                 // protect sh_f reuse
        }
    }

    // ---- sweep rows bottom-up, NT-store vtrace ----
    float4 x = carry;
    #pragma unroll
    for (int r = CHUNK_L - 1; r >= 0; --r) {
        x = f4_fma(bv[r], x, a4[r]);
        nt_store4(out_v + base + r * B_DIM, x);
    }

    // ---- publish inclusive (out[c*L] = x) ----
    {
        const int e = c * B_DIM + col;
        *(float4*)(incl + e) = x;
        __syncthreads();
        if (threadIdx.x == 0) {
            __threadfence();
            __hip_atomic_store(&flags[c * NCG + g], 2,
                               __ATOMIC_RELEASE, __HIP_MEMORY_SCOPE_AGENT);
        }
    }
}

extern "C" void kernel_launch(void* const* d_in, const int* in_sizes, int n_in,
                              void* d_out, int out_size, void* d_ws, size_t ws_size,
                              hipStream_t stream) {
    const float* v   = (const float*)d_in[0];
    const float* rew = (const float*)d_in[1];
    const float* tlp = (const float*)d_in[2];
    const float* blp = (const float*)d_in[3];

    float* out_v   = (float*)d_out;
    float* out_rho = out_v + (size_t)T_DIM * B_DIM;

    float* aggA = (float*)d_ws;                                  // 8 MiB
    float* aggB = aggA + (size_t)NCHUNK * B_DIM;                 // 8 MiB
    float* incl = aggB + (size_t)NCHUNK * B_DIM;                 // 8 MiB
    int*   flags = (int*)(incl + (size_t)NCHUNK * B_DIM);        // 8 KiB

    hipMemsetAsync(flags, 0, NCHUNK * NCG * sizeof(int), stream);

    dim3 blk(256);
    dim3 grid(NCG, NCHUNK);   // x fastest -> all col-groups of chunk 255 first
    vtrace_fused<<<grid, blk, 0, stream>>>(v, rew, tlp, blp,
                                           out_v, out_rho,
                                           aggA, aggB, incl, flags);
}

// Round 6
// 125.923 us; speedup vs baseline: 4.8831x; 4.8831x over previous
//
#include <hip/hip_runtime.h>

#define T_DIM 2048
#define B_DIM 8192
#define GAMMA 0.99f
#define NCHUNK 256
#define CHUNK_L 8            // rows per chunk (NCHUNK*CHUNK_L == T_DIM)

typedef float v4f __attribute__((ext_vector_type(4)));

__device__ __forceinline__ void nt_store4(float* p, float4 x) {
    __builtin_nontemporal_store(*(v4f*)&x, (v4f*)p);
}

// ---------------------------------------------------------------------------
// Pass 1, forced-deep-MLP version: issue ALL 32 global_load_dwordx4 (8 rows x
// 4 streams), then sched_barrier(0) so the compiler CANNOT sink loads to
// just-before-use (R4's silent failure: VGPR stayed 44 => ~2 outstanding
// loads/wave). Payload alone = 128 VGPR; expect ~160-200 total.
// Then compute rho, a=v+rho*(rew-v), b=gamma*rho (row T-1: a=v, b=0),
// chunk composite out[cL] = A + B*out[(c+1)L]; stores grouped at the end.
// ---------------------------------------------------------------------------
__global__ __launch_bounds__(256) void vtrace_pass1(
    const float* __restrict__ v, const float* __restrict__ rew,
    const float* __restrict__ tlp, const float* __restrict__ blp,
    float* __restrict__ out_a,      // d_out vtrace slot (temp: a)
    float* __restrict__ out_rho,    // d_out + T*B
    float* __restrict__ Aw, float* __restrict__ Bw)
{
    const int j    = blockIdx.x * blockDim.x + threadIdx.x;  // 0 .. B/4-1
    const int c    = blockIdx.y;
    const int col  = j * 4;
    const int base = c * CHUNK_L * B_DIM + col;

    // ---- phase 1: issue every load; fence so none can be sunk ----
    float4 t4[CHUNK_L], b4[CHUNK_L], v4[CHUNK_L], r4[CHUNK_L];
    #pragma unroll
    for (int r = 0; r < CHUNK_L; ++r)
        t4[r] = *(const float4*)(tlp + base + r * B_DIM);
    #pragma unroll
    for (int r = 0; r < CHUNK_L; ++r)
        b4[r] = *(const float4*)(blp + base + r * B_DIM);
    #pragma unroll
    for (int r = 0; r < CHUNK_L; ++r)
        v4[r] = *(const float4*)(v + base + r * B_DIM);
    #pragma unroll
    for (int r = 0; r < CHUNK_L; ++r)
        r4[r] = *(const float4*)(rew + base + r * B_DIM);

    __builtin_amdgcn_sched_barrier(0);   // loads stay issued above this line

    // ---- phase 2: compute everything in registers ----
    const bool last_chunk = (c == NCHUNK - 1);
    float4 rho[CHUNK_L], a4[CHUNK_L], bv[CHUNK_L];
    #pragma unroll
    for (int r = 0; r < CHUNK_L; ++r) {
        rho[r].x = fminf(1.f, __expf(t4[r].x - b4[r].x));
        rho[r].y = fminf(1.f, __expf(t4[r].y - b4[r].y));
        rho[r].z = fminf(1.f, __expf(t4[r].z - b4[r].z));
        rho[r].w = fminf(1.f, __expf(t4[r].w - b4[r].w));
    }
    #pragma unroll
    for (int r = 0; r < CHUNK_L; ++r) {
        if (last_chunk && r == CHUNK_L - 1) {        // global row T-1
            a4[r] = v4[r];
            bv[r] = make_float4(0.f, 0.f, 0.f, 0.f);
        } else {
            a4[r].x = fmaf(rho[r].x, r4[r].x - v4[r].x, v4[r].x);
            a4[r].y = fmaf(rho[r].y, r4[r].y - v4[r].y, v4[r].y);
            a4[r].z = fmaf(rho[r].z, r4[r].z - v4[r].z, v4[r].z);
            a4[r].w = fmaf(rho[r].w, r4[r].w - v4[r].w, v4[r].w);
            bv[r].x = GAMMA * rho[r].x;
            bv[r].y = GAMMA * rho[r].y;
            bv[r].z = GAMMA * rho[r].z;
            bv[r].w = GAMMA * rho[r].w;
        }
    }

    float4 A  = make_float4(0.f, 0.f, 0.f, 0.f);
    float4 Bc = make_float4(1.f, 1.f, 1.f, 1.f);
    #pragma unroll
    for (int r = CHUNK_L - 1; r >= 0; --r) {
        A.x = fmaf(bv[r].x, A.x, a4[r].x);
        A.y = fmaf(bv[r].y, A.y, a4[r].y);
        A.z = fmaf(bv[r].z, A.z, a4[r].z);
        A.w = fmaf(bv[r].w, A.w, a4[r].w);
        Bc.x *= bv[r].x; Bc.y *= bv[r].y; Bc.z *= bv[r].z; Bc.w *= bv[r].w;
    }

    // ---- phase 3: stores, grouped ----
    #pragma unroll
    for (int r = 0; r < CHUNK_L; ++r)
        *(float4*)(out_rho + base + r * B_DIM) = rho[r];
    #pragma unroll
    for (int r = 0; r < CHUNK_L; ++r)
        *(float4*)(out_a + base + r * B_DIM) = a4[r];

    const int widx = c * B_DIM + col;
    *(float4*)(Aw + widx) = A;
    *(float4*)(Bw + widx) = Bc;
}

// ---------------------------------------------------------------------------
// Pass 2: per-column right-to-left scan of chunk composites -> carries.
// cb[c] = value entering chunk c from the right, i.e. out[(c+1)*L].
// ---------------------------------------------------------------------------
__global__ __launch_bounds__(256) void vtrace_carry(
    const float* __restrict__ Aw, const float* __restrict__ Bw,
    float* __restrict__ cb)
{
    const int j = blockIdx.x * blockDim.x + threadIdx.x;  // 0 .. B-1
    float x = 0.f;
    #pragma unroll 8
    for (int c = NCHUNK - 1; c >= 0; --c) {
        const int i = c * B_DIM + j;
        const float Av = Aw[i];
        const float Bv = Bw[i];
        cb[i] = x;
        x = fmaf(Bv, x, Av);
    }
}

// ---------------------------------------------------------------------------
// Pass 3: apply recurrence within each chunk (a/rho are L2/L3-resident),
// vtrace written in place over a with NON-TEMPORAL stores (never re-read;
// keeps the inputs L3-resident for the next graph replay).
// ---------------------------------------------------------------------------
__global__ __launch_bounds__(256) void vtrace_apply(
    float* __restrict__ out_v,           // a in, vtrace out (in place)
    const float* __restrict__ rho_arr,
    const float* __restrict__ cb)
{
    const int j   = blockIdx.x * blockDim.x + threadIdx.x;  // 0 .. B/4-1
    const int c   = blockIdx.y;
    const int col = j * 4;
    const int t_hi = (c + 1) * CHUNK_L - 1;
    const int t_lo = c * CHUNK_L;

    float4 carry = *(const float4*)(cb + c * B_DIM + col);

    int idx = t_hi * B_DIM + col;
    #pragma unroll
    for (int t = t_hi; t >= t_lo; --t, idx -= B_DIM) {
        const float4 a4  = *(const float4*)(out_v   + idx);
        const float4 rho = *(const float4*)(rho_arr + idx);
        const float g = (t == T_DIM - 1) ? 0.f : GAMMA;
        float4 o;
        o.x = fmaf(g * rho.x, carry.x, a4.x);
        o.y = fmaf(g * rho.y, carry.y, a4.y);
        o.z = fmaf(g * rho.z, carry.z, a4.z);
        o.w = fmaf(g * rho.w, carry.w, a4.w);
        nt_store4(out_v + idx, o);
        carry = o;
    }
}

extern "C" void kernel_launch(void* const* d_in, const int* in_sizes, int n_in,
                              void* d_out, int out_size, void* d_ws, size_t ws_size,
                              hipStream_t stream) {
    const float* v   = (const float*)d_in[0];
    const float* rew = (const float*)d_in[1];
    const float* tlp = (const float*)d_in[2];
    const float* blp = (const float*)d_in[3];

    float* out_v   = (float*)d_out;                          // vtrace slot
    float* out_rho = out_v + (size_t)T_DIM * B_DIM;          // rhos slot

    float* Aw = (float*)d_ws;                                // NCHUNK*B floats
    float* Bw = Aw + (size_t)NCHUNK * B_DIM;                 // NCHUNK*B floats
    float* cb = Bw + (size_t)NCHUNK * B_DIM;                 // NCHUNK*B floats

    dim3 blk(256);
    dim3 grid_scan(B_DIM / 4 / 256, NCHUNK);                 // (8, 256)

    vtrace_pass1<<<grid_scan, blk, 0, stream>>>(v, rew, tlp, blp,
                                                out_v, out_rho, Aw, Bw);
    vtrace_carry<<<dim3(B_DIM / 256), blk, 0, stream>>>(Aw, Bw, cb);
    vtrace_apply<<<grid_scan, blk, 0, stream>>>(out_v, out_rho, cb);
}